// Round 2
// baseline (396.004 us; speedup 1.0000x reference)
//
#include <hip/hip_runtime.h>

#define NNODES 4096
#define NCH    128
#define NE     10
#define PADN   4736          // 74 chunks * 64 (worst-case 64-padded buckets)
#define NCHUNK 74
#define TSTRIDE 2048         // per-(e,c) table stride (floats)
#define DGSTRIDE 672         // per-dgroup interleaved stream stride (219*3=657, padded to x16)

// ---------------- workspace layout ----------------
// int   chunkinfo[80]            at ws[0..80)     (beg | valid<<16 | e<<24, -1 = unused)
// int   list[PADN]               at ws[80..4816)  (-1 = padding slot)
// float Sws[NE][NCH][TSTRIDE]    at ws[4864]      interleaved symmetric tables
// float pre[NCH][9][PADN]
// float xg [NCH][9][PADN]
// total ~54 MB

// ---------------- symmetric-stream decode table ----------------
struct MTab { unsigned short v[220]; };
static constexpr MTab make_mtab() {
    MTab t{};
    int m = 0;
    for (int i = 0; i < 9; ++i) {
        t.v[m++] = (unsigned short)((1 << 12) | (i << 8) | (i << 4) | i);
        for (int j = i; j < 9; ++j) {
            t.v[m++] = (unsigned short)((2 << 12) | (i << 8) | (j << 4) | j);
            for (int n = j; n < 9; ++n)
                t.v[m++] = (unsigned short)((3 << 12) | (i << 8) | (j << 4) | n);
        }
    }
    return t;   // m == 219
}
__constant__ MTab c_mtab = make_mtab();

// ---------------- fused bucketing: hist + scan + scatter + chunk table ----------------
__global__ __launch_bounds__(1024) void k_bucket(
    const float* __restrict__ attrs, int* __restrict__ list, int* __restrict__ chunkinfo)
{
    __shared__ int hist[NE], cur[NE], base[NE + 1], cbase[NE + 1];
    int t = threadIdx.x;
    if (t < NE) { hist[t] = 0; cur[t] = 0; }
    __syncthreads();
    int mye[4];
#pragma unroll
    for (int k = 0; k < 4; ++k) {
        int b = t * 4 + k;
        const float* y = attrs + (size_t)b * NE;
        int e = 0;
#pragma unroll
        for (int u = 0; u < NE; ++u) if (y[u] > 0.5f) e = u;
        mye[k] = e;
        atomicAdd(&hist[e], 1);
    }
    // init padded list while hist settles
    for (int i = t; i < PADN; i += 1024) list[i] = -1;
    __syncthreads();
    if (t == 0) {
        int off = 0, goff = 0;
        for (int e = 0; e < NE; ++e) {
            base[e] = off; cbase[e] = goff;
            int nc = (hist[e] + 63) >> 6;
            off += nc * 64; goff += nc;
        }
        base[NE] = off; cbase[NE] = goff;
    }
    __syncthreads();
    if (t < 80) {
        int info = -1;
        if (t < cbase[NE]) {
            int e = 0;
            while (!(t >= cbase[e] && t < cbase[e + 1])) ++e;
            int k = t - cbase[e];
            int valid = hist[e] - k * 64; if (valid > 64) valid = 64;
            info = (base[e] + k * 64) | (valid << 16) | (e << 24);
        }
        chunkinfo[t] = info;
    }
#pragma unroll
    for (int k = 0; k < 4; ++k) {
        int e = mye[k];
        int pos = atomicAdd(&cur[e], 1);
        list[base[e] + pos] = t * 4 + k;
    }
}

// 30-wide dot of one U3 row with per-lane w3
__device__ __forceinline__ float dot30(const float* __restrict__ U3, int dloc, int row,
                                       const float (&w3)[30])
{
    const float2* u = (const float2*)(U3 + ((size_t)dloc * 729 + row) * 30);
    float v = 0.0f;
#pragma unroll
    for (int kk = 0; kk < 15; ++kk) {
        float2 a = u[kk];
        v = fmaf(a.x, w3[2 * kk], v);
        v = fmaf(a.y, w3[2 * kk + 1], v);
    }
    return v;
}

// ---------------- fused gather + symmetric table precompute ----------------
// blocks [0,592): gather-transpose into padded xg (pads -> 0)
// blocks [592,1222): symmetric tables, interleaved-by-3 layout
__global__ __launch_bounds__(256) void k_gp(
    const float* __restrict__ nf, const int* __restrict__ list,
    const float* __restrict__ U3_0, const float* __restrict__ U3_1, const float* __restrict__ U3_2,
    const float* __restrict__ W3_0, const float* __restrict__ W3_1, const float* __restrict__ W3_2,
    const float* __restrict__ U2_0, const float* __restrict__ U2_1, const float* __restrict__ U2_2,
    const float* __restrict__ W2_0, const float* __restrict__ W2_1, const float* __restrict__ W2_2,
    const float* __restrict__ U1_0, const float* __restrict__ U1_1, const float* __restrict__ U1_2,
    const float* __restrict__ W1_0, const float* __restrict__ W1_1, const float* __restrict__ W1_2,
    float* __restrict__ xg, float* __restrict__ Sws)
{
    __shared__ __align__(16) float smem[64 * 145];
    __shared__ int lb[64];
    int bid = blockIdx.x, t = threadIdx.x;
    if (bid < 592) {
        // ---- gather-transpose: xg[(c*9+n)*PADN+q] = nf[(list[q]*128+c)*9+n], pad -> 0 ----
        int qb = bid >> 3, ct = bid & 7;
        int c0 = ct * 16;
        if (t < 64) lb[t] = list[qb * 64 + t];
        __syncthreads();
#pragma unroll 1
        for (int k = 0; k < 36; ++k) {
            int idx = k * 256 + t;                // 64 nodes * 144 elems
            int node = idx / 144, elem = idx - node * 144;
            int nb = lb[node];
            float v = 0.0f;
            if (nb >= 0) v = nf[((size_t)nb * 128 + c0) * 9 + elem];
            smem[node * 145 + elem] = v;
        }
        __syncthreads();
#pragma unroll 1
        for (int k = 0; k < 36; ++k) {
            int idx = k * 256 + t;
            int node = idx & 63, re = idx >> 6;
            xg[((size_t)(c0 * 9 + re)) * PADN + qb * 64 + node] = smem[node * 145 + re];
        }
    } else {
        // ---- symmetric table build: one (e, D), 32 stream entries x 128 c ----
        int bid2 = bid - 592;
        int e = bid2 / 63, r = bid2 - e * 63;
        int D = r / 7, chunk0 = (r - D * 7) * 32;
        int c = t & 127, sub = t >> 7;
        const float *U3, *U2, *U1, *W3, *W2, *W1; int dloc;
        if (D == 0)      { U3 = U3_0; U2 = U2_0; U1 = U1_0; W3 = W3_0; W2 = W2_0; W1 = W1_0; dloc = 0; }
        else if (D < 4)  { U3 = U3_1; U2 = U2_1; U1 = U1_1; W3 = W3_1; W2 = W2_1; W1 = W1_1; dloc = D - 1; }
        else             { U3 = U3_2; U2 = U2_2; U1 = U1_2; W3 = W3_2; W2 = W2_2; W1 = W1_2; dloc = D - 4; }
        float w3[30], w2[12], w1[4];
#pragma unroll
        for (int k = 0; k < 30; ++k) w3[k] = W3[((size_t)e * 30 + k) * 128 + c];
#pragma unroll
        for (int k = 0; k < 12; ++k) w2[k] = W2[((size_t)e * 12 + k) * 128 + c];
#pragma unroll
        for (int k = 0; k < 4; ++k)  w1[k] = W1[((size_t)e * 4 + k) * 128 + c];
        float* tile = smem;                       // 32*129 floats used
#pragma unroll 1
        for (int rr = sub * 16; rr < sub * 16 + 16; ++rr) {
            int m = chunk0 + rr;
            float val = 0.0f;
            if (m < 219) {
                unsigned mv = c_mtab.v[m];
                int kind = mv >> 12, i = (mv >> 8) & 15, j = (mv >> 4) & 15, n = mv & 15;
                if (kind == 1) {
                    const float* u = U1 + (size_t)(dloc * 9 + i) * 4;
#pragma unroll
                    for (int k = 0; k < 4; ++k) val = fmaf(u[k], w1[k], val);
                } else if (kind == 2) {
                    const float* ua = U2 + (size_t)(dloc * 81 + i * 9 + j) * 12;
#pragma unroll
                    for (int k = 0; k < 12; ++k) val = fmaf(ua[k], w2[k], val);
                    if (i != j) {
                        const float* ub = U2 + (size_t)(dloc * 81 + j * 9 + i) * 12;
#pragma unroll
                        for (int k = 0; k < 12; ++k) val = fmaf(ub[k], w2[k], val);
                    }
                } else {
                    int r1 = -1, r2 = -1, r3 = -1, r4 = -1, r5 = -1;
                    if (i == j) {
                        if (j != n) { r1 = i * 81 + n * 9 + i; r2 = n * 81 + i * 9 + i; }
                    } else if (j == n) {
                        r1 = j * 81 + i * 9 + j; r2 = j * 81 + j * 9 + i;
                    } else {
                        r1 = i * 81 + n * 9 + j; r2 = j * 81 + i * 9 + n;
                        r3 = j * 81 + n * 9 + i; r4 = n * 81 + i * 9 + j;
                        r5 = n * 81 + j * 9 + i;
                    }
                    val = dot30(U3, dloc, i * 81 + j * 9 + n, w3);
                    if (r1 >= 0) { val += dot30(U3, dloc, r1, w3); val += dot30(U3, dloc, r2, w3); }
                    if (r3 >= 0) {
                        val += dot30(U3, dloc, r3, w3); val += dot30(U3, dloc, r4, w3);
                        val += dot30(U3, dloc, r5, w3);
                    }
                }
            }
            tile[rr * 129 + c] = val;
        }
        __syncthreads();
        int dg = D / 3, dr = D - dg * 3;
#pragma unroll 1
        for (int wv = 0; wv < 16; ++wv) {
            int idx = t + 256 * wv;               // 32 entries * 128 c = 4096
            int cc = idx >> 5, rr = idx & 31;
            int m = chunk0 + rr;
            if (m < 219)
                Sws[((size_t)e * 128 + cc) * TSTRIDE + dg * DGSTRIDE + m * 3 + dr] = tile[rr * 129 + cc];
        }
    }
}

// ---------------- main contraction: 1 wave = 64 nodes, all 9 D ----------------
// out_D = sum_i x_i*(T1_i + sum_{j>=i} x_j*(S2_ij + sum_{n>=j} S3_ijn*x_n))
// Table stream interleaved by 3 D's -> 3 independent FMA chains, sequential
// wave-uniform s_load stream of 657 floats per dgroup.
__global__ __launch_bounds__(256) void k_main(
    const float* __restrict__ xg, const int* __restrict__ chunkinfo,
    const float* __restrict__ Sws, float* __restrict__ pre)
{
    int c = blockIdx.x;
    int w = threadIdx.x >> 6, lane = threadIdx.x & 63;
    int g = blockIdx.y * 4 + w;
    int info = chunkinfo[g];
    if (info == -1) return;
    int beg = info & 0xffff;
    int e = (info >> 24) & 0xff;
    int pos = beg + lane;

    const float* tab = Sws + ((size_t)e * NCH + c) * TSTRIDE;
    const float* xq  = xg + (size_t)c * 9 * PADN;
    float* prep      = pre + (size_t)c * 9 * PADN;

    float x[9];
#pragma unroll
    for (int n = 0; n < 9; ++n) x[n] = xq[(size_t)n * PADN + pos];

#pragma unroll 1
    for (int dg = 0; dg < 3; ++dg) {
        const float* s = tab + dg * DGSTRIDE;
        float a3[3] = {0.0f, 0.0f, 0.0f};
        int p = 0;
#pragma unroll
        for (int i = 0; i < 9; ++i) {
            float a2[3];
#pragma unroll
            for (int d = 0; d < 3; ++d) a2[d] = s[p + d];
            p += 3;
#pragma unroll
            for (int j = i; j < 9; ++j) {
                float a1[3];
#pragma unroll
                for (int d = 0; d < 3; ++d) a1[d] = s[p + d];
                p += 3;
#pragma unroll
                for (int n = j; n < 9; ++n) {
#pragma unroll
                    for (int d = 0; d < 3; ++d) a1[d] = fmaf(s[p + d], x[n], a1[d]);
                    p += 3;
                }
#pragma unroll
                for (int d = 0; d < 3; ++d) a2[d] = fmaf(a1[d], x[j], a2[d]);
            }
#pragma unroll
            for (int d = 0; d < 3; ++d) a3[d] = fmaf(a2[d], x[i], a3[d]);
        }
#pragma unroll
        for (int d = 0; d < 3; ++d)
            prep[(size_t)(dg * 3 + d) * PADN + pos] = a3[d];
    }
}

// ---------------- channel mix + permute + sc add ----------------
// block (chunk g, D), 256 thr = 4 f-groups x 64 q. Thread: 1 q x 32 f.
// lin rows are wave-uniform -> scalar loads; 32 independent FMA chains.
__global__ __launch_bounds__(256) void k_mixout(
    const float* __restrict__ pre, const int* __restrict__ list,
    const int* __restrict__ chunkinfo, const float* __restrict__ sc,
    const float* __restrict__ lin0, const float* __restrict__ lin1,
    const float* __restrict__ lin2, float* __restrict__ out)
{
    int g = blockIdx.x, D = blockIdx.y;
    if (chunkinfo[g] == -1) return;
    int t = threadIdx.x;
    int tq = t & 63;
    int f0 = __builtin_amdgcn_readfirstlane(t >> 6) * 32;
    int q = g * 64 + tq;
    const float* lin; int L, dl;
    if (D == 0)      { lin = lin0; L = 0; dl = 0; }
    else if (D < 4)  { lin = lin1; L = 1; dl = D - 1; }
    else             { lin = lin2; L = 2; dl = D - 4; }

    float acc[32];
#pragma unroll
    for (int f = 0; f < 32; ++f) acc[f] = 0.0f;

#pragma unroll 2
    for (int c = 0; c < 128; ++c) {
        float pv = pre[((size_t)c * 9 + D) * PADN + q];
        const float* lr = lin + c * 128 + f0;
#pragma unroll
        for (int f = 0; f < 32; ++f)
            acc[f] = fmaf(pv, lr[f], acc[f]);
    }

    int b = list[q];
    if (b < 0) return;
    const float nrm = 0.08838834764831845f;   // 1/sqrt(128)
    const float* scb = sc + (size_t)b * 1152;
    float* ob = out + (size_t)b * 1152;
    if (L == 0) {
#pragma unroll
        for (int f = 0; f < 32; ++f)
            ob[f0 + f] = fmaf(nrm, acc[f], scb[f0 + f]);
    } else if (L == 1) {
#pragma unroll
        for (int f = 0; f < 32; ++f) {
            int col = 128 + (f0 + f) * 3 + dl;
            ob[col] = fmaf(nrm, acc[f], scb[col]);
        }
    } else {
#pragma unroll
        for (int f = 0; f < 32; ++f) {
            int col = 512 + (f0 + f) * 5 + dl;
            ob[col] = fmaf(nrm, acc[f], scb[col]);
        }
    }
}

// ---------------- launch ----------------
extern "C" void kernel_launch(void* const* d_in, const int* in_sizes, int n_in,
                              void* d_out, int out_size, void* d_ws, size_t ws_size,
                              hipStream_t stream)
{
    const float* nf    = (const float*)d_in[0];
    const float* sc    = (const float*)d_in[1];
    const float* attrs = (const float*)d_in[2];
    const float *U3s[3], *U2s[3], *U1s[3], *W3s[3], *W2s[3], *W1s[3], *lins[3];
    for (int L = 0; L < 3; ++L) {
        const int o = 3 + 7 * L;
        U3s[L]  = (const float*)d_in[o + 0];
        U2s[L]  = (const float*)d_in[o + 1];
        U1s[L]  = (const float*)d_in[o + 2];
        W3s[L]  = (const float*)d_in[o + 3];
        W2s[L]  = (const float*)d_in[o + 4];
        W1s[L]  = (const float*)d_in[o + 5];
        lins[L] = (const float*)d_in[o + 6];
    }

    float* wsf     = (float*)d_ws;
    int* chunkinfo = (int*)d_ws;
    int* list      = chunkinfo + 80;
    float* Sws = wsf + 4864;
    float* pre = Sws + (size_t)NE * NCH * TSTRIDE;   // 2,621,440
    float* xg  = pre + (size_t)NCH * 9 * PADN;       // 5,455,872

    k_bucket<<<1, 1024, 0, stream>>>(attrs, list, chunkinfo);
    k_gp<<<1222, 256, 0, stream>>>(nf, list,
                                   U3s[0], U3s[1], U3s[2], W3s[0], W3s[1], W3s[2],
                                   U2s[0], U2s[1], U2s[2], W2s[0], W2s[1], W2s[2],
                                   U1s[0], U1s[1], U1s[2], W1s[0], W1s[1], W1s[2],
                                   xg, Sws);
    k_main<<<dim3(128, 19), 256, 0, stream>>>(xg, chunkinfo, Sws, pre);
    k_mixout<<<dim3(NCHUNK, 9), 256, 0, stream>>>(pre, list, chunkinfo, sc,
                                                  lins[0], lins[1], lins[2], (float*)d_out);
}

// Round 3
// 309.638 us; speedup vs baseline: 1.2789x; 1.2789x over previous
//
#include <hip/hip_runtime.h>

#define NNODES 4096
#define NCH    128
#define NE     10
#define PADN   4736          // 74 chunks * 64 (worst-case 64-padded buckets)
#define NCHUNK 74
#define TSTRIDE 2048         // per-(e,c) table stride (floats)
#define DGSTRIDE 672         // per-dgroup interleaved stream stride (219*3=657, padded to x16)

// ---------------- workspace layout ----------------
// int   chunkinfo[80]            at ws[0..80)     (beg | valid<<16 | e<<24, -1 = unused)
// int   list[PADN]               at ws[80..4816)  (-1 = padding slot)
// float Sws[NE][NCH][TSTRIDE]    at ws[4864]      interleaved symmetric tables
// float pre[NCH][9][PADN]
// float xg [NCH][9][PADN]
// total ~54 MB

// ---------------- symmetric-stream decode table ----------------
struct MTab { unsigned short v[220]; };
static constexpr MTab make_mtab() {
    MTab t{};
    int m = 0;
    for (int i = 0; i < 9; ++i) {
        t.v[m++] = (unsigned short)((1 << 12) | (i << 8) | (i << 4) | i);
        for (int j = i; j < 9; ++j) {
            t.v[m++] = (unsigned short)((2 << 12) | (i << 8) | (j << 4) | j);
            for (int n = j; n < 9; ++n)
                t.v[m++] = (unsigned short)((3 << 12) | (i << 8) | (j << 4) | n);
        }
    }
    return t;   // m == 219
}
__constant__ MTab c_mtab = make_mtab();

// ---------------- fused bucketing: hist + scan + scatter + chunk table ----------------
__global__ __launch_bounds__(1024) void k_bucket(
    const float* __restrict__ attrs, int* __restrict__ list, int* __restrict__ chunkinfo)
{
    __shared__ int hist[NE], cur[NE], base[NE + 1], cbase[NE + 1];
    int t = threadIdx.x;
    if (t < NE) { hist[t] = 0; cur[t] = 0; }
    __syncthreads();
    int mye[4];
#pragma unroll
    for (int k = 0; k < 4; ++k) {
        int b = t * 4 + k;
        const float* y = attrs + (size_t)b * NE;
        int e = 0;
#pragma unroll
        for (int u = 0; u < NE; ++u) if (y[u] > 0.5f) e = u;
        mye[k] = e;
        atomicAdd(&hist[e], 1);
    }
    // init padded list while hist settles
    for (int i = t; i < PADN; i += 1024) list[i] = -1;
    __syncthreads();
    if (t == 0) {
        int off = 0, goff = 0;
        for (int e = 0; e < NE; ++e) {
            base[e] = off; cbase[e] = goff;
            int nc = (hist[e] + 63) >> 6;
            off += nc * 64; goff += nc;
        }
        base[NE] = off; cbase[NE] = goff;
    }
    __syncthreads();
    if (t < 80) {
        int info = -1;
        if (t < cbase[NE]) {
            int e = 0;
            while (!(t >= cbase[e] && t < cbase[e + 1])) ++e;
            int k = t - cbase[e];
            int valid = hist[e] - k * 64; if (valid > 64) valid = 64;
            info = (base[e] + k * 64) | (valid << 16) | (e << 24);
        }
        chunkinfo[t] = info;
    }
#pragma unroll
    for (int k = 0; k < 4; ++k) {
        int e = mye[k];
        int pos = atomicAdd(&cur[e], 1);
        list[base[e] + pos] = t * 4 + k;
    }
}

// 30-wide dot of one U3 row with per-lane w3
__device__ __forceinline__ float dot30(const float* __restrict__ U3, int dloc, int row,
                                       const float (&w3)[30])
{
    const float2* u = (const float2*)(U3 + ((size_t)dloc * 729 + row) * 30);
    float v = 0.0f;
#pragma unroll
    for (int kk = 0; kk < 15; ++kk) {
        float2 a = u[kk];
        v = fmaf(a.x, w3[2 * kk], v);
        v = fmaf(a.y, w3[2 * kk + 1], v);
    }
    return v;
}

// ---------------- fused gather + symmetric table precompute ----------------
// blocks [0,592): gather-transpose into padded xg (pads -> 0)
// blocks [592,1222): symmetric tables, interleaved-by-3 layout
__global__ __launch_bounds__(256) void k_gp(
    const float* __restrict__ nf, const int* __restrict__ list,
    const float* __restrict__ U3_0, const float* __restrict__ U3_1, const float* __restrict__ U3_2,
    const float* __restrict__ W3_0, const float* __restrict__ W3_1, const float* __restrict__ W3_2,
    const float* __restrict__ U2_0, const float* __restrict__ U2_1, const float* __restrict__ U2_2,
    const float* __restrict__ W2_0, const float* __restrict__ W2_1, const float* __restrict__ W2_2,
    const float* __restrict__ U1_0, const float* __restrict__ U1_1, const float* __restrict__ U1_2,
    const float* __restrict__ W1_0, const float* __restrict__ W1_1, const float* __restrict__ W1_2,
    float* __restrict__ xg, float* __restrict__ Sws)
{
    __shared__ __align__(16) float smem[64 * 145];
    __shared__ int lb[64];
    int bid = blockIdx.x, t = threadIdx.x;
    if (bid < 592) {
        // ---- gather-transpose: xg[(c*9+n)*PADN+q] = nf[(list[q]*128+c)*9+n], pad -> 0 ----
        int qb = bid >> 3, ct = bid & 7;
        int c0 = ct * 16;
        if (t < 64) lb[t] = list[qb * 64 + t];
        __syncthreads();
#pragma unroll 1
        for (int k = 0; k < 36; ++k) {
            int idx = k * 256 + t;                // 64 nodes * 144 elems
            int node = idx / 144, elem = idx - node * 144;
            int nb = lb[node];
            float v = 0.0f;
            if (nb >= 0) v = nf[((size_t)nb * 128 + c0) * 9 + elem];
            smem[node * 145 + elem] = v;
        }
        __syncthreads();
#pragma unroll 1
        for (int k = 0; k < 36; ++k) {
            int idx = k * 256 + t;
            int node = idx & 63, re = idx >> 6;
            xg[((size_t)(c0 * 9 + re)) * PADN + qb * 64 + node] = smem[node * 145 + re];
        }
    } else {
        // ---- symmetric table build: one (e, D), 32 stream entries x 128 c ----
        int bid2 = bid - 592;
        int e = bid2 / 63, r = bid2 - e * 63;
        int D = r / 7, chunk0 = (r - D * 7) * 32;
        int c = t & 127, sub = t >> 7;
        const float *U3, *U2, *U1, *W3, *W2, *W1; int dloc;
        if (D == 0)      { U3 = U3_0; U2 = U2_0; U1 = U1_0; W3 = W3_0; W2 = W2_0; W1 = W1_0; dloc = 0; }
        else if (D < 4)  { U3 = U3_1; U2 = U2_1; U1 = U1_1; W3 = W3_1; W2 = W2_1; W1 = W1_1; dloc = D - 1; }
        else             { U3 = U3_2; U2 = U2_2; U1 = U1_2; W3 = W3_2; W2 = W2_2; W1 = W1_2; dloc = D - 4; }
        float w3[30], w2[12], w1[4];
#pragma unroll
        for (int k = 0; k < 30; ++k) w3[k] = W3[((size_t)e * 30 + k) * 128 + c];
#pragma unroll
        for (int k = 0; k < 12; ++k) w2[k] = W2[((size_t)e * 12 + k) * 128 + c];
#pragma unroll
        for (int k = 0; k < 4; ++k)  w1[k] = W1[((size_t)e * 4 + k) * 128 + c];
        float* tile = smem;                       // 32*129 floats used
#pragma unroll 1
        for (int rr = sub * 16; rr < sub * 16 + 16; ++rr) {
            int m = chunk0 + rr;
            float val = 0.0f;
            if (m < 219) {
                unsigned mv = c_mtab.v[m];
                int kind = mv >> 12, i = (mv >> 8) & 15, j = (mv >> 4) & 15, n = mv & 15;
                if (kind == 1) {
                    const float* u = U1 + (size_t)(dloc * 9 + i) * 4;
#pragma unroll
                    for (int k = 0; k < 4; ++k) val = fmaf(u[k], w1[k], val);
                } else if (kind == 2) {
                    const float* ua = U2 + (size_t)(dloc * 81 + i * 9 + j) * 12;
#pragma unroll
                    for (int k = 0; k < 12; ++k) val = fmaf(ua[k], w2[k], val);
                    if (i != j) {
                        const float* ub = U2 + (size_t)(dloc * 81 + j * 9 + i) * 12;
#pragma unroll
                        for (int k = 0; k < 12; ++k) val = fmaf(ub[k], w2[k], val);
                    }
                } else {
                    int r1 = -1, r2 = -1, r3 = -1, r4 = -1, r5 = -1;
                    if (i == j) {
                        if (j != n) { r1 = i * 81 + n * 9 + i; r2 = n * 81 + i * 9 + i; }
                    } else if (j == n) {
                        r1 = j * 81 + i * 9 + j; r2 = j * 81 + j * 9 + i;
                    } else {
                        r1 = i * 81 + n * 9 + j; r2 = j * 81 + i * 9 + n;
                        r3 = j * 81 + n * 9 + i; r4 = n * 81 + i * 9 + j;
                        r5 = n * 81 + j * 9 + i;
                    }
                    val = dot30(U3, dloc, i * 81 + j * 9 + n, w3);
                    if (r1 >= 0) { val += dot30(U3, dloc, r1, w3); val += dot30(U3, dloc, r2, w3); }
                    if (r3 >= 0) {
                        val += dot30(U3, dloc, r3, w3); val += dot30(U3, dloc, r4, w3);
                        val += dot30(U3, dloc, r5, w3);
                    }
                }
            }
            tile[rr * 129 + c] = val;
        }
        __syncthreads();
        int dg = D / 3, dr = D - dg * 3;
#pragma unroll 1
        for (int wv = 0; wv < 16; ++wv) {
            int idx = t + 256 * wv;               // 32 entries * 128 c = 4096
            int cc = idx >> 5, rr = idx & 31;
            int m = chunk0 + rr;
            if (m < 219)
                Sws[((size_t)e * 128 + cc) * TSTRIDE + dg * DGSTRIDE + m * 3 + dr] = tile[rr * 129 + cc];
        }
    }
}

// ---------------- main contraction: 1 wave = 64 nodes, all 9 D ----------------
// out_D = sum_i x_i*(T1_i + sum_{j>=i} x_j*(S2_ij + sum_{n>=j} S3_ijn*x_n))
// Per-wave table staged in its own LDS slice (8 KB), then read with
// wave-uniform broadcast ds_reads (conflict-free, merged to b128).
// 3 D's interleaved -> 3 independent FMA chains.
__global__ __launch_bounds__(256) void k_main(
    const float* __restrict__ xg, const int* __restrict__ chunkinfo,
    const float* __restrict__ Sws, float* __restrict__ pre)
{
    __shared__ __align__(16) float tabs[4][TSTRIDE];   // 32 KB, one slice per wave
    int c = blockIdx.x;
    int w = threadIdx.x >> 6, lane = threadIdx.x & 63;
    int g = blockIdx.y * 4 + w;
    int info = __builtin_amdgcn_readfirstlane(chunkinfo[g]);
    if (info == -1) return;
    int beg = info & 0xffff;
    int e = (info >> 24) & 0xff;
    int pos = beg + lane;

    // ---- stage this wave's (e,c) table into LDS (coalesced, 8 x float4/lane) ----
    {
        const float4* src = (const float4*)(Sws + ((size_t)e * NCH + c) * TSTRIDE);
        float4* dst = (float4*)tabs[w];
#pragma unroll
        for (int k = 0; k < 8; ++k)
            dst[lane + k * 64] = src[lane + k * 64];
    }

    const float* xq = xg + (size_t)c * 9 * PADN;
    float* prep     = pre + (size_t)c * 9 * PADN;

    float x[9];
#pragma unroll
    for (int n = 0; n < 9; ++n) x[n] = xq[(size_t)n * PADN + pos];

#pragma unroll 1
    for (int dg = 0; dg < 3; ++dg) {
        const float* s = tabs[w] + dg * DGSTRIDE;   // LDS, wave-uniform addrs
        float a3[3] = {0.0f, 0.0f, 0.0f};
        int p = 0;
#pragma unroll
        for (int i = 0; i < 9; ++i) {
            float a2[3];
#pragma unroll
            for (int d = 0; d < 3; ++d) a2[d] = s[p + d];
            p += 3;
#pragma unroll
            for (int j = i; j < 9; ++j) {
                float a1[3];
#pragma unroll
                for (int d = 0; d < 3; ++d) a1[d] = s[p + d];
                p += 3;
#pragma unroll
                for (int n = j; n < 9; ++n) {
#pragma unroll
                    for (int d = 0; d < 3; ++d) a1[d] = fmaf(s[p + d], x[n], a1[d]);
                    p += 3;
                }
#pragma unroll
                for (int d = 0; d < 3; ++d) a2[d] = fmaf(a1[d], x[j], a2[d]);
            }
#pragma unroll
            for (int d = 0; d < 3; ++d) a3[d] = fmaf(a2[d], x[i], a3[d]);
        }
#pragma unroll
        for (int d = 0; d < 3; ++d)
            prep[(size_t)(dg * 3 + d) * PADN + pos] = a3[d];
    }
}

// ---------------- channel mix + permute + sc add ----------------
// block (chunk g, D), 256 thr = 4 f-groups x 64 q. Thread: 1 q x 32 f.
// lin rows are wave-uniform -> scalar loads; 32 independent FMA chains.
__global__ __launch_bounds__(256) void k_mixout(
    const float* __restrict__ pre, const int* __restrict__ list,
    const int* __restrict__ chunkinfo, const float* __restrict__ sc,
    const float* __restrict__ lin0, const float* __restrict__ lin1,
    const float* __restrict__ lin2, float* __restrict__ out)
{
    int g = blockIdx.x, D = blockIdx.y;
    if (chunkinfo[g] == -1) return;
    int t = threadIdx.x;
    int tq = t & 63;
    int f0 = __builtin_amdgcn_readfirstlane(t >> 6) * 32;
    int q = g * 64 + tq;
    const float* lin; int L, dl;
    if (D == 0)      { lin = lin0; L = 0; dl = 0; }
    else if (D < 4)  { lin = lin1; L = 1; dl = D - 1; }
    else             { lin = lin2; L = 2; dl = D - 4; }

    float acc[32];
#pragma unroll
    for (int f = 0; f < 32; ++f) acc[f] = 0.0f;

#pragma unroll 2
    for (int c = 0; c < 128; ++c) {
        float pv = pre[((size_t)c * 9 + D) * PADN + q];
        const float* lr = lin + c * 128 + f0;
#pragma unroll
        for (int f = 0; f < 32; ++f)
            acc[f] = fmaf(pv, lr[f], acc[f]);
    }

    int b = list[q];
    if (b < 0) return;
    const float nrm = 0.08838834764831845f;   // 1/sqrt(128)
    const float* scb = sc + (size_t)b * 1152;
    float* ob = out + (size_t)b * 1152;
    if (L == 0) {
#pragma unroll
        for (int f = 0; f < 32; ++f)
            ob[f0 + f] = fmaf(nrm, acc[f], scb[f0 + f]);
    } else if (L == 1) {
#pragma unroll
        for (int f = 0; f < 32; ++f) {
            int col = 128 + (f0 + f) * 3 + dl;
            ob[col] = fmaf(nrm, acc[f], scb[col]);
        }
    } else {
#pragma unroll
        for (int f = 0; f < 32; ++f) {
            int col = 512 + (f0 + f) * 5 + dl;
            ob[col] = fmaf(nrm, acc[f], scb[col]);
        }
    }
}

// ---------------- launch ----------------
extern "C" void kernel_launch(void* const* d_in, const int* in_sizes, int n_in,
                              void* d_out, int out_size, void* d_ws, size_t ws_size,
                              hipStream_t stream)
{
    const float* nf    = (const float*)d_in[0];
    const float* sc    = (const float*)d_in[1];
    const float* attrs = (const float*)d_in[2];
    const float *U3s[3], *U2s[3], *U1s[3], *W3s[3], *W2s[3], *W1s[3], *lins[3];
    for (int L = 0; L < 3; ++L) {
        const int o = 3 + 7 * L;
        U3s[L]  = (const float*)d_in[o + 0];
        U2s[L]  = (const float*)d_in[o + 1];
        U1s[L]  = (const float*)d_in[o + 2];
        W3s[L]  = (const float*)d_in[o + 3];
        W2s[L]  = (const float*)d_in[o + 4];
        W1s[L]  = (const float*)d_in[o + 5];
        lins[L] = (const float*)d_in[o + 6];
    }

    float* wsf     = (float*)d_ws;
    int* chunkinfo = (int*)d_ws;
    int* list      = chunkinfo + 80;
    float* Sws = wsf + 4864;
    float* pre = Sws + (size_t)NE * NCH * TSTRIDE;   // 2,621,440
    float* xg  = pre + (size_t)NCH * 9 * PADN;       // 5,455,872

    k_bucket<<<1, 1024, 0, stream>>>(attrs, list, chunkinfo);
    k_gp<<<1222, 256, 0, stream>>>(nf, list,
                                   U3s[0], U3s[1], U3s[2], W3s[0], W3s[1], W3s[2],
                                   U2s[0], U2s[1], U2s[2], W2s[0], W2s[1], W2s[2],
                                   U1s[0], U1s[1], U1s[2], W1s[0], W1s[1], W1s[2],
                                   xg, Sws);
    k_main<<<dim3(128, 19), 256, 0, stream>>>(xg, chunkinfo, Sws, pre);
    k_mixout<<<dim3(NCHUNK, 9), 256, 0, stream>>>(pre, list, chunkinfo, sc,
                                                  lins[0], lins[1], lins[2], (float*)d_out);
}

// Round 4
// 294.384 us; speedup vs baseline: 1.3452x; 1.0518x over previous
//
#include <hip/hip_runtime.h>

#define NNODES 4096
#define NCH    128
#define NE     10
#define PADN   4736          // 74 chunks * 64 (worst-case 64-padded buckets)
#define NCHUNK 74
#define TSTRIDE 2048         // per-(e,c) table stride (floats)
#define DGSTRIDE 672         // per-dgroup interleaved stream stride (219*3=657, padded to x16)

// ---------------- workspace layout ----------------
// int   chunkinfo[80]            at ws[0..80)     (beg | valid<<16 | e<<24, -1 = unused)
// int   list[PADN]               at ws[80..4816)  (-1 = padding slot)
// float Sws[NE][NCH][TSTRIDE]    at ws[4864]      interleaved symmetric tables
// float pre[NCH][9][PADN]
// float xg [NCH][9][PADN]
// total ~54 MB

// ---------------- symmetric-stream decode table ----------------
struct MTab { unsigned short v[220]; };
static constexpr MTab make_mtab() {
    MTab t{};
    int m = 0;
    for (int i = 0; i < 9; ++i) {
        t.v[m++] = (unsigned short)((1 << 12) | (i << 8) | (i << 4) | i);
        for (int j = i; j < 9; ++j) {
            t.v[m++] = (unsigned short)((2 << 12) | (i << 8) | (j << 4) | j);
            for (int n = j; n < 9; ++n)
                t.v[m++] = (unsigned short)((3 << 12) | (i << 8) | (j << 4) | n);
        }
    }
    return t;   // m == 219
}
__constant__ MTab c_mtab = make_mtab();

// 30-wide dot of one U3 row with per-lane w3
__device__ __forceinline__ float dot30(const float* __restrict__ U3, int dloc, int row,
                                       const float (&w3)[30])
{
    const float2* u = (const float2*)(U3 + ((size_t)dloc * 729 + row) * 30);
    float v = 0.0f;
#pragma unroll
    for (int kk = 0; kk < 15; ++kk) {
        float2 a = u[kk];
        v = fmaf(a.x, w3[2 * kk], v);
        v = fmaf(a.y, w3[2 * kk + 1], v);
    }
    return v;
}

// ---------------- fused: symmetric table build (blocks 0..629) + bucketing (block 630) ----------------
// Table blocks are independent of node data; bucket block (histogram+scan+scatter)
// runs concurrently instead of serializing the whole GPU.
__global__ __launch_bounds__(256) void k_pre(
    const float* __restrict__ attrs,
    const float* __restrict__ U3_0, const float* __restrict__ U3_1, const float* __restrict__ U3_2,
    const float* __restrict__ W3_0, const float* __restrict__ W3_1, const float* __restrict__ W3_2,
    const float* __restrict__ U2_0, const float* __restrict__ U2_1, const float* __restrict__ U2_2,
    const float* __restrict__ W2_0, const float* __restrict__ W2_1, const float* __restrict__ W2_2,
    const float* __restrict__ U1_0, const float* __restrict__ U1_1, const float* __restrict__ U1_2,
    const float* __restrict__ W1_0, const float* __restrict__ W1_1, const float* __restrict__ W1_2,
    float* __restrict__ Sws, int* __restrict__ list, int* __restrict__ chunkinfo)
{
    __shared__ __align__(16) float tile[32 * 129];
    int bid = blockIdx.x, t = threadIdx.x;
    if (bid < 630) {
        // ---- symmetric table build: one (e, D), 32 stream entries x 128 c ----
        int e = bid / 63, r = bid - e * 63;
        int D = r / 7, chunk0 = (r - D * 7) * 32;
        int c = t & 127, sub = t >> 7;
        const float *U3, *U2, *U1, *W3, *W2, *W1; int dloc;
        if (D == 0)      { U3 = U3_0; U2 = U2_0; U1 = U1_0; W3 = W3_0; W2 = W2_0; W1 = W1_0; dloc = 0; }
        else if (D < 4)  { U3 = U3_1; U2 = U2_1; U1 = U1_1; W3 = W3_1; W2 = W2_1; W1 = W1_1; dloc = D - 1; }
        else             { U3 = U3_2; U2 = U2_2; U1 = U1_2; W3 = W3_2; W2 = W2_2; W1 = W1_2; dloc = D - 4; }
        float w3[30], w2[12], w1[4];
#pragma unroll
        for (int k = 0; k < 30; ++k) w3[k] = W3[((size_t)e * 30 + k) * 128 + c];
#pragma unroll
        for (int k = 0; k < 12; ++k) w2[k] = W2[((size_t)e * 12 + k) * 128 + c];
#pragma unroll
        for (int k = 0; k < 4; ++k)  w1[k] = W1[((size_t)e * 4 + k) * 128 + c];
#pragma unroll 1
        for (int rr = sub * 16; rr < sub * 16 + 16; ++rr) {
            int m = chunk0 + rr;
            float val = 0.0f;
            if (m < 219) {
                unsigned mv = c_mtab.v[m];
                int kind = mv >> 12, i = (mv >> 8) & 15, j = (mv >> 4) & 15, n = mv & 15;
                if (kind == 1) {
                    const float* u = U1 + (size_t)(dloc * 9 + i) * 4;
#pragma unroll
                    for (int k = 0; k < 4; ++k) val = fmaf(u[k], w1[k], val);
                } else if (kind == 2) {
                    const float* ua = U2 + (size_t)(dloc * 81 + i * 9 + j) * 12;
#pragma unroll
                    for (int k = 0; k < 12; ++k) val = fmaf(ua[k], w2[k], val);
                    if (i != j) {
                        const float* ub = U2 + (size_t)(dloc * 81 + j * 9 + i) * 12;
#pragma unroll
                        for (int k = 0; k < 12; ++k) val = fmaf(ub[k], w2[k], val);
                    }
                } else {
                    int r1 = -1, r2 = -1, r3 = -1, r4 = -1, r5 = -1;
                    if (i == j) {
                        if (j != n) { r1 = i * 81 + n * 9 + i; r2 = n * 81 + i * 9 + i; }
                    } else if (j == n) {
                        r1 = j * 81 + i * 9 + j; r2 = j * 81 + j * 9 + i;
                    } else {
                        r1 = i * 81 + n * 9 + j; r2 = j * 81 + i * 9 + n;
                        r3 = j * 81 + n * 9 + i; r4 = n * 81 + i * 9 + j;
                        r5 = n * 81 + j * 9 + i;
                    }
                    val = dot30(U3, dloc, i * 81 + j * 9 + n, w3);
                    if (r1 >= 0) { val += dot30(U3, dloc, r1, w3); val += dot30(U3, dloc, r2, w3); }
                    if (r3 >= 0) {
                        val += dot30(U3, dloc, r3, w3); val += dot30(U3, dloc, r4, w3);
                        val += dot30(U3, dloc, r5, w3);
                    }
                }
            }
            tile[rr * 129 + c] = val;
        }
        __syncthreads();
        int dg = D / 3, dr = D - dg * 3;
#pragma unroll 1
        for (int wv = 0; wv < 16; ++wv) {
            int idx = t + 256 * wv;               // 32 entries * 128 c = 4096
            int cc = idx >> 5, rr = idx & 31;
            int m = chunk0 + rr;
            if (m < 219)
                Sws[((size_t)e * 128 + cc) * TSTRIDE + dg * DGSTRIDE + m * 3 + dr] = tile[rr * 129 + cc];
        }
    } else {
        // ---- bucketing: hist + scan + scatter + chunk table (single block) ----
        __shared__ int hist[NE], cur[NE], base[NE + 1], cbase[NE + 1];
        if (t < NE) { hist[t] = 0; cur[t] = 0; }
        __syncthreads();
        int mye[16];
#pragma unroll
        for (int k = 0; k < 16; ++k) {
            int b = k * 256 + t;
            const float* y = attrs + (size_t)b * NE;
            int e = 0;
#pragma unroll
            for (int u = 0; u < NE; ++u) if (y[u] > 0.5f) e = u;
            mye[k] = e;
            atomicAdd(&hist[e], 1);
        }
        for (int i = t; i < PADN; i += 256) list[i] = -1;
        __syncthreads();
        if (t == 0) {
            int off = 0, goff = 0;
            for (int e = 0; e < NE; ++e) {
                base[e] = off; cbase[e] = goff;
                int nc = (hist[e] + 63) >> 6;
                off += nc * 64; goff += nc;
            }
            base[NE] = off; cbase[NE] = goff;
        }
        __syncthreads();
        if (t < 80) {
            int info = -1;
            if (t < cbase[NE]) {
                int e = 0;
                while (!(t >= cbase[e] && t < cbase[e + 1])) ++e;
                int k = t - cbase[e];
                int valid = hist[e] - k * 64; if (valid > 64) valid = 64;
                info = (base[e] + k * 64) | (valid << 16) | (e << 24);
            }
            chunkinfo[t] = info;
        }
#pragma unroll
        for (int k = 0; k < 16; ++k) {
            int e = mye[k];
            int pos = atomicAdd(&cur[e], 1);
            list[base[e] + pos] = k * 256 + t;
        }
    }
}

// ---------------- gather-transpose: xg[(c*9+n)*PADN+q] = nf[(list[q]*128+c)*9+n] ----------------
// 64 nodes x 8 channels per block -> 1184 blocks, 18.7 KB LDS, 8 blocks/CU.
__global__ __launch_bounds__(256) void k_gather(
    const float* __restrict__ nf, const int* __restrict__ list, float* __restrict__ xg)
{
    __shared__ __align__(16) float smem[64 * 73];
    __shared__ int lb[64];
    int qb = blockIdx.x >> 4, ct = blockIdx.x & 15;
    int c0 = ct * 8;
    int t = threadIdx.x;
    if (t < 64) lb[t] = list[qb * 64 + t];
    __syncthreads();
#pragma unroll 1
    for (int k = 0; k < 18; ++k) {
        int idx = k * 256 + t;                    // 64 nodes * 72 elems
        int node = idx / 72, elem = idx - node * 72;
        int nb = lb[node];
        float v = 0.0f;
        if (nb >= 0) v = nf[(size_t)nb * 1152 + c0 * 9 + elem];
        smem[node * 73 + elem] = v;
    }
    __syncthreads();
#pragma unroll 1
    for (int k = 0; k < 18; ++k) {
        int idx = k * 256 + t;
        int node = idx & 63, re = idx >> 6;       // re in [0,72)
        xg[((size_t)(c0 * 9 + re)) * PADN + qb * 64 + node] = smem[node * 73 + re];
    }
}

// ---------------- main contraction: 1 wave = 64 nodes, all 9 D ----------------
// out_D = sum_i x_i*(T1_i + sum_{j>=i} x_j*(S2_ij + sum_{n>=j} S3_ijn*x_n))
// Per-wave table staged in its own LDS slice (8 KB), then read with
// wave-uniform broadcast ds_reads (conflict-free, merged to b128).
// 3 D's interleaved -> 3 independent FMA chains.
__global__ __launch_bounds__(256) void k_main(
    const float* __restrict__ xg, const int* __restrict__ chunkinfo,
    const float* __restrict__ Sws, float* __restrict__ pre)
{
    __shared__ __align__(16) float tabs[4][TSTRIDE];   // 32 KB, one slice per wave
    int c = blockIdx.x;
    int w = threadIdx.x >> 6, lane = threadIdx.x & 63;
    int g = blockIdx.y * 4 + w;
    int info = __builtin_amdgcn_readfirstlane(chunkinfo[g]);
    if (info == -1) return;
    int beg = info & 0xffff;
    int e = (info >> 24) & 0xff;
    int pos = beg + lane;

    // ---- stage this wave's (e,c) table into LDS (coalesced, 8 x float4/lane) ----
    {
        const float4* src = (const float4*)(Sws + ((size_t)e * NCH + c) * TSTRIDE);
        float4* dst = (float4*)tabs[w];
#pragma unroll
        for (int k = 0; k < 8; ++k)
            dst[lane + k * 64] = src[lane + k * 64];
    }

    const float* xq = xg + (size_t)c * 9 * PADN;
    float* prep     = pre + (size_t)c * 9 * PADN;

    float x[9];
#pragma unroll
    for (int n = 0; n < 9; ++n) x[n] = xq[(size_t)n * PADN + pos];

#pragma unroll 1
    for (int dg = 0; dg < 3; ++dg) {
        const float* s = tabs[w] + dg * DGSTRIDE;   // LDS, wave-uniform addrs
        float a3[3] = {0.0f, 0.0f, 0.0f};
        int p = 0;
#pragma unroll
        for (int i = 0; i < 9; ++i) {
            float a2[3];
#pragma unroll
            for (int d = 0; d < 3; ++d) a2[d] = s[p + d];
            p += 3;
#pragma unroll
            for (int j = i; j < 9; ++j) {
                float a1[3];
#pragma unroll
                for (int d = 0; d < 3; ++d) a1[d] = s[p + d];
                p += 3;
#pragma unroll
                for (int n = j; n < 9; ++n) {
#pragma unroll
                    for (int d = 0; d < 3; ++d) a1[d] = fmaf(s[p + d], x[n], a1[d]);
                    p += 3;
                }
#pragma unroll
                for (int d = 0; d < 3; ++d) a2[d] = fmaf(a1[d], x[j], a2[d]);
            }
#pragma unroll
            for (int d = 0; d < 3; ++d) a3[d] = fmaf(a2[d], x[i], a3[d]);
        }
#pragma unroll
        for (int d = 0; d < 3; ++d)
            prep[(size_t)(dg * 3 + d) * PADN + pos] = a3[d];
    }
}

// ---------------- channel mix + permute + sc add ----------------
// block (chunk g, D): stage pre tile [128c][64q] in LDS (coalesced float4),
// then thread = (q, 32-f group): pre via conflict-free ds_read broadcast,
// lin rows via wave-uniform s_load. 32 independent FMA chains.
__global__ __launch_bounds__(256) void k_mixout(
    const float* __restrict__ pre, const int* __restrict__ list,
    const int* __restrict__ chunkinfo, const float* __restrict__ sc,
    const float* __restrict__ lin0, const float* __restrict__ lin1,
    const float* __restrict__ lin2, float* __restrict__ out)
{
    __shared__ __align__(16) float pt[128 * 64];   // 32 KB
    int g = blockIdx.x, D = blockIdx.y;
    if (chunkinfo[g] == -1) return;
    int t = threadIdx.x;

    // ---- stage: 8 float4 per thread, fully parallel coalesced loads ----
    {
        int q4 = (t & 15) * 4;
        int cb = t >> 4;                           // 0..15
#pragma unroll
        for (int k = 0; k < 8; ++k) {
            int c = cb + k * 16;
            float4 v = *(const float4*)&pre[((size_t)c * 9 + D) * PADN + g * 64 + q4];
            *(float4*)&pt[c * 64 + q4] = v;
        }
    }
    __syncthreads();

    int tq = t & 63;
    int f0 = __builtin_amdgcn_readfirstlane(t >> 6) * 32;
    int q = g * 64 + tq;
    const float* lin; int L, dl;
    if (D == 0)      { lin = lin0; L = 0; dl = 0; }
    else if (D < 4)  { lin = lin1; L = 1; dl = D - 1; }
    else             { lin = lin2; L = 2; dl = D - 4; }

    float acc[32];
#pragma unroll
    for (int f = 0; f < 32; ++f) acc[f] = 0.0f;

#pragma unroll 4
    for (int c = 0; c < 128; ++c) {
        float pv = pt[c * 64 + tq];
        const float* lr = lin + c * 128 + f0;
#pragma unroll
        for (int f = 0; f < 32; ++f)
            acc[f] = fmaf(pv, lr[f], acc[f]);
    }

    int b = list[q];
    if (b < 0) return;
    const float nrm = 0.08838834764831845f;   // 1/sqrt(128)
    const float* scb = sc + (size_t)b * 1152;
    float* ob = out + (size_t)b * 1152;
    if (L == 0) {
#pragma unroll
        for (int f = 0; f < 32; ++f)
            ob[f0 + f] = fmaf(nrm, acc[f], scb[f0 + f]);
    } else if (L == 1) {
#pragma unroll
        for (int f = 0; f < 32; ++f) {
            int col = 128 + (f0 + f) * 3 + dl;
            ob[col] = fmaf(nrm, acc[f], scb[col]);
        }
    } else {
#pragma unroll
        for (int f = 0; f < 32; ++f) {
            int col = 512 + (f0 + f) * 5 + dl;
            ob[col] = fmaf(nrm, acc[f], scb[col]);
        }
    }
}

// ---------------- launch ----------------
extern "C" void kernel_launch(void* const* d_in, const int* in_sizes, int n_in,
                              void* d_out, int out_size, void* d_ws, size_t ws_size,
                              hipStream_t stream)
{
    const float* nf    = (const float*)d_in[0];
    const float* sc    = (const float*)d_in[1];
    const float* attrs = (const float*)d_in[2];
    const float *U3s[3], *U2s[3], *U1s[3], *W3s[3], *W2s[3], *W1s[3], *lins[3];
    for (int L = 0; L < 3; ++L) {
        const int o = 3 + 7 * L;
        U3s[L]  = (const float*)d_in[o + 0];
        U2s[L]  = (const float*)d_in[o + 1];
        U1s[L]  = (const float*)d_in[o + 2];
        W3s[L]  = (const float*)d_in[o + 3];
        W2s[L]  = (const float*)d_in[o + 4];
        W1s[L]  = (const float*)d_in[o + 5];
        lins[L] = (const float*)d_in[o + 6];
    }

    float* wsf     = (float*)d_ws;
    int* chunkinfo = (int*)d_ws;
    int* list      = chunkinfo + 80;
    float* Sws = wsf + 4864;
    float* pre = Sws + (size_t)NE * NCH * TSTRIDE;   // 2,621,440
    float* xg  = pre + (size_t)NCH * 9 * PADN;       // 5,455,872

    k_pre<<<631, 256, 0, stream>>>(attrs,
                                   U3s[0], U3s[1], U3s[2], W3s[0], W3s[1], W3s[2],
                                   U2s[0], U2s[1], U2s[2], W2s[0], W2s[1], W2s[2],
                                   U1s[0], U1s[1], U1s[2], W1s[0], W1s[1], W1s[2],
                                   Sws, list, chunkinfo);
    k_gather<<<1184, 256, 0, stream>>>(nf, list, xg);
    k_main<<<dim3(128, 19), 256, 0, stream>>>(xg, chunkinfo, Sws, pre);
    k_mixout<<<dim3(NCHUNK, 9), 256, 0, stream>>>(pre, list, chunkinfo, sc,
                                                  lins[0], lins[1], lins[2], (float*)d_out);
}